// Round 1
// baseline (871.775 us; speedup 1.0000x reference)
//
#include <hip/hip_runtime.h>

#define T_STEPS 512
#define BATCH   512
#define INPUT   32
#define HID     64
#define NGATES  256   // 4*HID
#define CH      64    // h1 chunk steps staged in LDS (layer 1)

__device__ __forceinline__ float fast_sigmoid(float x) {
    return 1.0f / (1.0f + __expf(-x));
}
__device__ __forceinline__ float fast_tanh(float x) {
    // tanh(x) = 1 - 2/(1+e^{2x}); saturates correctly at +-inf, no NaN.
    return 1.0f - 2.0f / (1.0f + __expf(2.0f * x));
}

// Layer 0: x[B,T,32] -> h1[B,T,64]. One block per batch row; thread g owns gate g.
__global__ __launch_bounds__(256, 2)
void lstm_layer0(const float* __restrict__ x,
                 const float* __restrict__ W_ih,   // [256,32]
                 const float* __restrict__ W_hh,   // [256,64]
                 const float* __restrict__ b_ih,   // [256]
                 const float* __restrict__ b_hh,   // [256]
                 float* __restrict__ h1out)        // [B,T,64]
{
    __shared__ float xs[T_STEPS * INPUT];   // 64 KB: whole x row
    __shared__ float gates_s[NGATES];
    __shared__ float hbuf[HID];

    const int b = blockIdx.x;
    const int g = threadIdx.x;

    // Weight rows into registers (persist across all 512 steps).
    float wih[INPUT];
    float whh[HID];
    {
        const float4* wr = reinterpret_cast<const float4*>(W_ih + (size_t)g * INPUT);
        #pragma unroll
        for (int k = 0; k < INPUT / 4; ++k) {
            float4 v = wr[k];
            wih[4*k+0] = v.x; wih[4*k+1] = v.y; wih[4*k+2] = v.z; wih[4*k+3] = v.w;
        }
        const float4* hr = reinterpret_cast<const float4*>(W_hh + (size_t)g * HID);
        #pragma unroll
        for (int k = 0; k < HID / 4; ++k) {
            float4 v = hr[k];
            whh[4*k+0] = v.x; whh[4*k+1] = v.y; whh[4*k+2] = v.z; whh[4*k+3] = v.w;
        }
    }
    const float bias = b_ih[g] + b_hh[g];

    // Stage the whole x row (coalesced float4).
    {
        const float4* src = reinterpret_cast<const float4*>(x + (size_t)b * T_STEPS * INPUT);
        float4* dst = reinterpret_cast<float4*>(xs);
        for (int i = threadIdx.x; i < T_STEPS * INPUT / 4; i += 256) dst[i] = src[i];
    }
    if (g < HID) hbuf[g] = 0.0f;
    float c = 0.0f;
    __syncthreads();

    for (int t = 0; t < T_STEPS; ++t) {
        float acc = bias;
        const float* xt = xs + t * INPUT;
        #pragma unroll
        for (int k = 0; k < INPUT; ++k) acc = fmaf(wih[k], xt[k], acc);
        #pragma unroll
        for (int k = 0; k < HID; ++k)   acc = fmaf(whh[k], hbuf[k], acc);

        // gate order i,f,g,o: rows 128..191 are the tanh 'g' gate.
        float a = (g >= 2 * HID && g < 3 * HID) ? fast_tanh(acc) : fast_sigmoid(acc);
        gates_s[g] = a;
        __syncthreads();

        if (g < HID) {
            float i_ = gates_s[g];
            float f_ = gates_s[HID + g];
            float g_ = gates_s[2 * HID + g];
            float o_ = gates_s[3 * HID + g];
            c = fmaf(f_, c, i_ * g_);
            float h = o_ * fast_tanh(c);
            hbuf[g] = h;
            h1out[((size_t)b * T_STEPS + t) * HID + g] = h;
        }
        __syncthreads();
    }
}

// Layer 1: h1[B,T,64] -> out[B] (FC fused on last step).
__global__ __launch_bounds__(256, 2)
void lstm_layer1(const float* __restrict__ h1,
                 const float* __restrict__ W_ih,   // [256,64]
                 const float* __restrict__ W_hh,   // [256,64]
                 const float* __restrict__ b_ih,
                 const float* __restrict__ b_hh,
                 const float* __restrict__ W_fc,   // [1,64]
                 const float* __restrict__ b_fc,   // [1]
                 float* __restrict__ out)          // [B]
{
    __shared__ float xs[CH * HID];          // 16 KB chunk of h1
    __shared__ float gates_s[NGATES];
    __shared__ float hbuf[HID];

    const int b = blockIdx.x;
    const int g = threadIdx.x;

    float wih[HID];
    float whh[HID];
    {
        const float4* xr = reinterpret_cast<const float4*>(W_ih + (size_t)g * HID);
        #pragma unroll
        for (int k = 0; k < HID / 4; ++k) {
            float4 v = xr[k];
            wih[4*k+0] = v.x; wih[4*k+1] = v.y; wih[4*k+2] = v.z; wih[4*k+3] = v.w;
        }
        const float4* hr = reinterpret_cast<const float4*>(W_hh + (size_t)g * HID);
        #pragma unroll
        for (int k = 0; k < HID / 4; ++k) {
            float4 v = hr[k];
            whh[4*k+0] = v.x; whh[4*k+1] = v.y; whh[4*k+2] = v.z; whh[4*k+3] = v.w;
        }
    }
    const float bias = b_ih[g] + b_hh[g];

    if (g < HID) hbuf[g] = 0.0f;
    float c = 0.0f;
    __syncthreads();

    for (int t = 0; t < T_STEPS; ++t) {
        if ((t & (CH - 1)) == 0) {
            // Stage next CH steps of h1 for this row (coalesced).
            const float4* src = reinterpret_cast<const float4*>(
                h1 + ((size_t)b * T_STEPS + t) * HID);
            float4* dst = reinterpret_cast<float4*>(xs);
            for (int i = threadIdx.x; i < CH * HID / 4; i += 256) dst[i] = src[i];
            __syncthreads();
        }
        const float* xt = xs + (t & (CH - 1)) * HID;

        float acc = bias;
        #pragma unroll
        for (int k = 0; k < HID; ++k) acc = fmaf(wih[k], xt[k], acc);
        #pragma unroll
        for (int k = 0; k < HID; ++k) acc = fmaf(whh[k], hbuf[k], acc);

        float a = (g >= 2 * HID && g < 3 * HID) ? fast_tanh(acc) : fast_sigmoid(acc);
        gates_s[g] = a;
        __syncthreads();

        if (g < HID) {
            float i_ = gates_s[g];
            float f_ = gates_s[HID + g];
            float g_ = gates_s[2 * HID + g];
            float o_ = gates_s[3 * HID + g];
            c = fmaf(f_, c, i_ * g_);
            float h = o_ * fast_tanh(c);
            hbuf[g] = h;
        }
        __syncthreads();
    }

    // FC: out[b] = dot(W_fc, h2_last) + b_fc. Threads 0..63 = lanes 0..63 of wave 0.
    if (g < HID) {
        float v = hbuf[g] * W_fc[g];
        #pragma unroll
        for (int off = 32; off > 0; off >>= 1) v += __shfl_down(v, off);
        if (g == 0) out[b] = v + b_fc[0];
    }
}

extern "C" void kernel_launch(void* const* d_in, const int* in_sizes, int n_in,
                              void* d_out, int out_size, void* d_ws, size_t ws_size,
                              hipStream_t stream) {
    const float* x     = (const float*)d_in[0];
    const float* W_ih0 = (const float*)d_in[1];
    const float* W_hh0 = (const float*)d_in[2];
    const float* b_ih0 = (const float*)d_in[3];
    const float* b_hh0 = (const float*)d_in[4];
    const float* W_ih1 = (const float*)d_in[5];
    const float* W_hh1 = (const float*)d_in[6];
    const float* b_ih1 = (const float*)d_in[7];
    const float* b_hh1 = (const float*)d_in[8];
    const float* W_fc  = (const float*)d_in[9];
    const float* b_fc  = (const float*)d_in[10];

    float* out = (float*)d_out;
    float* h1  = (float*)d_ws;   // [512,512,64] f32 = 64 MB scratch

    lstm_layer0<<<BATCH, 256, 0, stream>>>(x, W_ih0, W_hh0, b_ih0, b_hh0, h1);
    lstm_layer1<<<BATCH, 256, 0, stream>>>(h1, W_ih1, W_hh1, b_ih1, b_hh1,
                                           W_fc, b_fc, out);
}

// Round 2
// 865.581 us; speedup vs baseline: 1.0072x; 1.0072x over previous
//
#include <hip/hip_runtime.h>

#define T_STEPS 512
#define BATCH   512
#define INPUT   32
#define HID     64
#define NGATES  256   // 4*HID
#define CH      64    // h1 chunk steps staged in LDS (layer 1)

// Force a value to live in a VGPR (breaks load provenance so the compiler
// cannot rematerialize the weight loads inside the recurrent loop).
#define PIN(x) asm volatile("" : "+v"(x))

__device__ __forceinline__ float fast_sigmoid(float x) {
    return 1.0f / (1.0f + __expf(-x));
}
__device__ __forceinline__ float fast_tanh(float x) {
    // tanh(x) = 1 - 2/(1+e^{2x}); saturates correctly at +-inf, no NaN.
    return 1.0f - 2.0f / (1.0f + __expf(2.0f * x));
}

// Layer 0: x[B,T,32] -> h1[B,T,64]. One block per batch row; thread g owns gate g.
// Occupancy is grid-limited to 2 waves/SIMD, so allow the full 256-VGPR budget.
__global__ __launch_bounds__(256, 2) __attribute__((amdgpu_waves_per_eu(2, 2)))
void lstm_layer0(const float* __restrict__ x,
                 const float* __restrict__ W_ih,   // [256,32]
                 const float* __restrict__ W_hh,   // [256,64]
                 const float* __restrict__ b_ih,   // [256]
                 const float* __restrict__ b_hh,   // [256]
                 float* __restrict__ h1out)        // [B,T,64]
{
    __shared__ __align__(16) float xs[T_STEPS * INPUT];   // 64 KB: whole x row
    __shared__ __align__(16) float gates_s[NGATES];
    __shared__ __align__(16) float hbuf[HID];

    const int b = blockIdx.x;
    const int g = threadIdx.x;
    const int lane = g & 63;

    // Weight rows into registers (persist across all 512 steps).
    float wih[INPUT];
    float whh[HID];
    {
        const float4* wr = reinterpret_cast<const float4*>(W_ih + (size_t)g * INPUT);
        #pragma unroll
        for (int k = 0; k < INPUT / 4; ++k) {
            float4 v = wr[k];
            wih[4*k+0] = v.x; wih[4*k+1] = v.y; wih[4*k+2] = v.z; wih[4*k+3] = v.w;
        }
        const float4* hr = reinterpret_cast<const float4*>(W_hh + (size_t)g * HID);
        #pragma unroll
        for (int k = 0; k < HID / 4; ++k) {
            float4 v = hr[k];
            whh[4*k+0] = v.x; whh[4*k+1] = v.y; whh[4*k+2] = v.z; whh[4*k+3] = v.w;
        }
        #pragma unroll
        for (int k = 0; k < INPUT; ++k) PIN(wih[k]);
        #pragma unroll
        for (int k = 0; k < HID; ++k)   PIN(whh[k]);
    }
    const float bias = b_ih[g] + b_hh[g];

    // Stage the whole x row (coalesced float4).
    {
        const float4* src = reinterpret_cast<const float4*>(x + (size_t)b * T_STEPS * INPUT);
        float4* dst = reinterpret_cast<float4*>(xs);
        for (int i = threadIdx.x; i < T_STEPS * INPUT / 4; i += 256) dst[i] = src[i];
    }
    if (g < HID) hbuf[g] = 0.0f;
    float c = 0.0f;
    __syncthreads();

    for (int t = 0; t < T_STEPS; ++t) {
        const float4* xt4 = reinterpret_cast<const float4*>(xs + t * INPUT);
        const float4* hb4 = reinterpret_cast<const float4*>(hbuf);

        // 4 independent accumulator chains (hide 4-cyc FMA latency at 2 waves/SIMD).
        float a0 = bias, a1 = 0.0f, a2 = 0.0f, a3 = 0.0f;
        #pragma unroll
        for (int k = 0; k < INPUT / 4; ++k) {
            float4 v = xt4[k];
            a0 = fmaf(wih[4*k+0], v.x, a0);
            a1 = fmaf(wih[4*k+1], v.y, a1);
            a2 = fmaf(wih[4*k+2], v.z, a2);
            a3 = fmaf(wih[4*k+3], v.w, a3);
        }
        #pragma unroll
        for (int k = 0; k < HID / 4; ++k) {
            float4 v = hb4[k];
            a0 = fmaf(whh[4*k+0], v.x, a0);
            a1 = fmaf(whh[4*k+1], v.y, a1);
            a2 = fmaf(whh[4*k+2], v.z, a2);
            a3 = fmaf(whh[4*k+3], v.w, a3);
        }
        float acc = (a0 + a1) + (a2 + a3);

        // gate order i,f,g,o: rows 128..191 (exactly wave 2) are the tanh gate.
        float a = (g >= 2 * HID && g < 3 * HID) ? fast_tanh(acc) : fast_sigmoid(acc);
        gates_s[g] = a;
        __syncthreads();

        // Redundant c/h update in all 4 waves (no idle-wave phase).
        float i_ = gates_s[lane];
        float f_ = gates_s[HID + lane];
        float g_ = gates_s[2 * HID + lane];
        float o_ = gates_s[3 * HID + lane];
        c = fmaf(f_, c, i_ * g_);
        float h = o_ * fast_tanh(c);
        if (g < HID) {
            hbuf[g] = h;
            h1out[((size_t)b * T_STEPS + t) * HID + g] = h;
        }
        __syncthreads();
    }
}

// Layer 1: h1[B,T,64] -> out[B] (FC fused on last step).
__global__ __launch_bounds__(256, 2) __attribute__((amdgpu_waves_per_eu(2, 2)))
void lstm_layer1(const float* __restrict__ h1,
                 const float* __restrict__ W_ih,   // [256,64]
                 const float* __restrict__ W_hh,   // [256,64]
                 const float* __restrict__ b_ih,
                 const float* __restrict__ b_hh,
                 const float* __restrict__ W_fc,   // [1,64]
                 const float* __restrict__ b_fc,   // [1]
                 float* __restrict__ out)          // [B]
{
    __shared__ __align__(16) float xs[CH * HID];          // 16 KB chunk of h1
    __shared__ __align__(16) float gates_s[NGATES];
    __shared__ __align__(16) float hbuf[HID];

    const int b = blockIdx.x;
    const int g = threadIdx.x;
    const int lane = g & 63;

    float wih[HID];
    float whh[HID];
    {
        const float4* xr = reinterpret_cast<const float4*>(W_ih + (size_t)g * HID);
        #pragma unroll
        for (int k = 0; k < HID / 4; ++k) {
            float4 v = xr[k];
            wih[4*k+0] = v.x; wih[4*k+1] = v.y; wih[4*k+2] = v.z; wih[4*k+3] = v.w;
        }
        const float4* hr = reinterpret_cast<const float4*>(W_hh + (size_t)g * HID);
        #pragma unroll
        for (int k = 0; k < HID / 4; ++k) {
            float4 v = hr[k];
            whh[4*k+0] = v.x; whh[4*k+1] = v.y; whh[4*k+2] = v.z; whh[4*k+3] = v.w;
        }
        #pragma unroll
        for (int k = 0; k < HID; ++k) PIN(wih[k]);
        #pragma unroll
        for (int k = 0; k < HID; ++k) PIN(whh[k]);
    }
    const float bias = b_ih[g] + b_hh[g];

    if (g < HID) hbuf[g] = 0.0f;
    float c = 0.0f;
    __syncthreads();

    for (int t = 0; t < T_STEPS; ++t) {
        if ((t & (CH - 1)) == 0) {
            // Stage next CH steps of h1 for this row (coalesced).
            // Safe WAR-wise: all threads passed the previous step's last barrier.
            const float4* src = reinterpret_cast<const float4*>(
                h1 + ((size_t)b * T_STEPS + t) * HID);
            float4* dst = reinterpret_cast<float4*>(xs);
            for (int i = threadIdx.x; i < CH * HID / 4; i += 256) dst[i] = src[i];
            __syncthreads();
        }
        const float4* xt4 = reinterpret_cast<const float4*>(xs + (t & (CH - 1)) * HID);
        const float4* hb4 = reinterpret_cast<const float4*>(hbuf);

        float a0 = bias, a1 = 0.0f, a2 = 0.0f, a3 = 0.0f;
        #pragma unroll
        for (int k = 0; k < HID / 4; ++k) {
            float4 v = xt4[k];
            a0 = fmaf(wih[4*k+0], v.x, a0);
            a1 = fmaf(wih[4*k+1], v.y, a1);
            a2 = fmaf(wih[4*k+2], v.z, a2);
            a3 = fmaf(wih[4*k+3], v.w, a3);
        }
        #pragma unroll
        for (int k = 0; k < HID / 4; ++k) {
            float4 v = hb4[k];
            a0 = fmaf(whh[4*k+0], v.x, a0);
            a1 = fmaf(whh[4*k+1], v.y, a1);
            a2 = fmaf(whh[4*k+2], v.z, a2);
            a3 = fmaf(whh[4*k+3], v.w, a3);
        }
        float acc = (a0 + a1) + (a2 + a3);

        float a = (g >= 2 * HID && g < 3 * HID) ? fast_tanh(acc) : fast_sigmoid(acc);
        gates_s[g] = a;
        __syncthreads();

        float i_ = gates_s[lane];
        float f_ = gates_s[HID + lane];
        float g_ = gates_s[2 * HID + lane];
        float o_ = gates_s[3 * HID + lane];
        c = fmaf(f_, c, i_ * g_);
        float h = o_ * fast_tanh(c);
        if (g < HID) hbuf[g] = h;
        __syncthreads();
    }

    // FC: out[b] = dot(W_fc, h2_last) + b_fc. Threads 0..63 = wave 0.
    if (g < HID) {
        float v = hbuf[g] * W_fc[g];
        #pragma unroll
        for (int off = 32; off > 0; off >>= 1) v += __shfl_down(v, off);
        if (g == 0) out[b] = v + b_fc[0];
    }
}

extern "C" void kernel_launch(void* const* d_in, const int* in_sizes, int n_in,
                              void* d_out, int out_size, void* d_ws, size_t ws_size,
                              hipStream_t stream) {
    const float* x     = (const float*)d_in[0];
    const float* W_ih0 = (const float*)d_in[1];
    const float* W_hh0 = (const float*)d_in[2];
    const float* b_ih0 = (const float*)d_in[3];
    const float* b_hh0 = (const float*)d_in[4];
    const float* W_ih1 = (const float*)d_in[5];
    const float* W_hh1 = (const float*)d_in[6];
    const float* b_ih1 = (const float*)d_in[7];
    const float* b_hh1 = (const float*)d_in[8];
    const float* W_fc  = (const float*)d_in[9];
    const float* b_fc  = (const float*)d_in[10];

    float* out = (float*)d_out;
    float* h1  = (float*)d_ws;   // [512,512,64] f32 = 64 MB scratch

    lstm_layer0<<<BATCH, 256, 0, stream>>>(x, W_ih0, W_hh0, b_ih0, b_hh0, h1);
    lstm_layer1<<<BATCH, 256, 0, stream>>>(h1, W_ih1, W_hh1, b_ih1, b_hh1,
                                           W_fc, b_fc, out);
}